// Round 6
// baseline (3308.095 us; speedup 1.0000x reference)
//
#include <hip/hip_runtime.h>

#define N_NODES 500000
typedef unsigned int u32;
typedef unsigned short u16;

// ===========================================================================
// R15: per-XCD partial accumulators + non-coherent (local-L2) FAF f32 atomics.
// R14 post-mortem: unsafeAtomicAdd = device-scope -> executed MEMORY-SIDE
// (WRITE_SIZE ~1GB for a 4MB acc, ~48cyc/atomic). Fix: accumulate into
// 8 per-XCD partials indexed by HW XCC_ID; plain global_atomic_add_f32
// (no sc1) executes in the LOCAL L2 (correct because each partial is only
// ever touched by one XCD; dirty lines flush at dispatch end). Node passes
// sum the 8 partials coalesced. Deg counting folded into the build kernel.
// Mid-tier: R9 gather path (ws ~76MB) if the 108MB fast layout doesn't fit.
//   fast rec = src_local9<<19 | dst19   per 512-node SRC bucket.
//   mid  rec = dst_local9<<19 | src19   per 512-node DST bucket.
// ===========================================================================
#define NPB    512
#define NBUCK  ((N_NODES + NPB - 1) / NPB)   // 977
#define CAP    17408          // mean fill 16376, sigma~128 -> 8s headroom
#define CH     8192           // edges per scatter chunk/WG
#define EPT    8              // edges per thread in scatter (CH / 1024)
#define STB    1024           // scatter block
#define LTB    512            // layer block
#define MASK19 0x7FFFFu

typedef unsigned int v4u __attribute__((ext_vector_type(4)));
__device__ inline int  nt1i(const int* p) { return __builtin_nontemporal_load(p); }
__device__ inline u32  nt1u(const u32* p) { return __builtin_nontemporal_load(p); }
__device__ inline v4u  nt4u(const u32* p) { return __builtin_nontemporal_load((const v4u*)p); }

// hardware XCD id (0..7 on MI355X) — all waves of a WG share a CU/XCD.
__device__ inline u32 xcc_id() {
    u32 x;
    asm("s_getreg_b32 %0, hwreg(HW_REG_XCC_ID)" : "=s"(x));
    return x & 7u;
}
// fire-and-forget f32 add, NO sc1 -> executes in the local (XCD) L2.
// Safe only because each partial plane is updated by exactly one XCD.
__device__ inline void faa(float* p, float v) {
    asm volatile("global_atomic_add_f32 %0, %1, off" :: "v"(p), "v"(v));
}
__device__ inline void vdrain() { asm volatile("s_waitcnt vmcnt(0)"); }

// ---- fused scatter build: edges register-cached; LDS histogram + scan +
//      presort; coalesced run writes into fixed bucket regions.
//      KS=1: key=src, payload=dst, also counts deg[dst] into per-XCD partial.
//      KS=0: key=dst, payload=src (R9 mid-tier form), degp unused.
template<int KS>
__global__ __launch_bounds__(STB) void k_scatter_fused(
        const int* __restrict__ src, const int* __restrict__ dst, int E,
        u32* __restrict__ cur_g, u32* __restrict__ rec,
        float* __restrict__ degp) {
    __shared__ u32 srec[CH];        // 32 KB
    __shared__ u16 sbk[CH];         // 16 KB
    __shared__ u32 hist[NBUCK];     // 3.9 KB
    __shared__ u32 sc[1024];        // 4 KB
    __shared__ u32 scn_ex[NBUCK];
    __shared__ u32 cur2[NBUCK];
    __shared__ u32 gbase[NBUCK];
    int tid = threadIdx.x, bid = blockIdx.x;
    float* dp = KS ? (degp + (size_t)xcc_id() * N_NODES) : degp;
    for (int b = tid; b < NBUCK; b += STB) hist[b] = 0;
    __syncthreads();
    int e0 = bid * CH, e1 = min(E, e0 + CH), n = e1 - e0;
    u32 kv[EPT], ov[EPT];           // key / other
#pragma unroll
    for (int k = 0; k < EPT; ++k) {
        int e = e0 + (k << 10) + tid;
        if (e < e1) {
            u32 d = (u32)nt1i(dst + e);
            u32 s = (u32)nt1i(src + e);
            kv[k] = KS ? s : d;
            ov[k] = KS ? d : s;
            atomicAdd(&hist[kv[k] >> 9], 1u);
            if (KS) faa(dp + d, 1.0f);          // deg[dst] += 1 (local-L2 FAF)
        }
    }
    __syncthreads();
    // scan over 1024 slots (Hillis-Steele)
    sc[tid] = (tid < NBUCK) ? hist[tid] : 0u;
    __syncthreads();
    for (int off = 1; off < 1024; off <<= 1) {
        u32 t = (tid >= off) ? sc[tid - off] : 0u;
        __syncthreads();
        sc[tid] += t;
        __syncthreads();
    }
    if (tid < NBUCK) {
        u32 ex = sc[tid] - hist[tid];
        scn_ex[tid] = ex;
        cur2[tid] = ex;
        gbase[tid] = hist[tid] ? atomicAdd(&cur_g[tid], hist[tid]) : 0u;
    }
    __syncthreads();
    // presort into LDS from registers
#pragma unroll
    for (int k = 0; k < EPT; ++k) {
        int e = e0 + (k << 10) + tid;
        if (e < e1) {
            u32 b = kv[k] >> 9;
            u32 p = atomicAdd(&cur2[b], 1u);
            srec[p] = ((kv[k] & (NPB - 1u)) << 19) | ov[k];
            sbk[p] = (u16)b;
        }
    }
    __syncthreads();
    // coalesced run writes into bucket regions
    for (int p = tid; p < n; p += STB) {
        u32 b = sbk[p];
        u32 slot = gbase[b] + ((u32)p - scn_ex[b]);
        rec[(size_t)b * CAP + slot] = srec[p];
    }
    if (KS) vdrain();
}

// =========================== FAST (scatter) tier ===========================
// ---- node pass 1: deg = sum of 8 partials; dis = rsqrt(deg+1); m1 = dis*x
__global__ void k_node1(const float* __restrict__ degp, const float* __restrict__ x,
                        float* __restrict__ dis, float* __restrict__ m1, int N) {
    int i = blockIdx.x * blockDim.x + threadIdx.x;
    if (i >= N) return;
    float s = 0.f;
#pragma unroll
    for (int k = 0; k < 8; ++k) s += degp[(size_t)k * N_NODES + i];
    float r = rsqrtf(s + 1.0f);                 // +1 self-loop
    dis[i] = r;
    m1[i] = r * x[i];
}

// ---- layer-1 scatter: stage m1[src tile] in LDS; acc1p[xcd][dst] += m1[src]
__global__ __launch_bounds__(LTB) void k_l1_scatter(
        const u32* __restrict__ rec, const u32* __restrict__ cnt_g,
        const float* __restrict__ m1, float* __restrict__ acc1p) {
    __shared__ float sm[NPB];
    int tid = threadIdx.x, bid = blockIdx.x;
    int node0 = bid << 9;
    int nn = min(NPB, N_NODES - node0);
    for (int l = tid; l < nn; l += LTB) sm[l] = m1[node0 + l];
    __syncthreads();
    float* base = acc1p + (size_t)xcc_id() * N_NODES;
    const u32* r0 = rec + (size_t)bid * CAP;
    u32 n = cnt_g[bid];
    u32 nv = n >> 2;
    for (u32 i = tid; i < nv; i += LTB) {
        v4u r = nt4u(r0 + ((size_t)i << 2));
        faa(base + (r.x & MASK19), sm[r.x >> 19]);
        faa(base + (r.y & MASK19), sm[r.y >> 19]);
        faa(base + (r.z & MASK19), sm[r.z >> 19]);
        faa(base + (r.w & MASK19), sm[r.w >> 19]);
    }
    for (u32 e = (nv << 2) + tid; e < n; e += LTB) {
        u32 r = nt1u(r0 + e);
        faa(base + (r & MASK19), sm[r >> 19]);
    }
    vdrain();
}

// ---- node pass 2: s = d*(sum acc1p + m1); MLP; h2m = d*h2
__global__ void k_node2(const float* __restrict__ dis, const float* __restrict__ m1,
                        const float* __restrict__ acc1p,
                        const float* __restrict__ W1, const float* __restrict__ b1,
                        const float* __restrict__ W2, const float* __restrict__ b2,
                        float2* __restrict__ h2m, int N) {
    int i = blockIdx.x * blockDim.x + threadIdx.x;
    if (i >= N) return;
    float a = 0.f;
#pragma unroll
    for (int k = 0; k < 8; ++k) a += acc1p[(size_t)k * N_NODES + i];
    float d = dis[i];
    float s = d * (a + m1[i]);
    float a0 = 0.f, a1 = 0.f;
#pragma unroll
    for (int k = 0; k < 8; ++k) {
        float h = fmaxf(W1[k] * s + b1[k], 0.f);
        a0 += h * W2[2 * k + 0];
        a1 += h * W2[2 * k + 1];
    }
    h2m[i] = make_float2(d * a0, d * a1);       // dis[src]*h2
}

// ---- layer-2 scatter: stage h2m[src tile]; acc2p[xcd][dst] += h2m[src]
__global__ __launch_bounds__(LTB) void k_l2_scatter(
        const u32* __restrict__ rec, const u32* __restrict__ cnt_g,
        const float2* __restrict__ h2m, float* __restrict__ acc2p) {
    __shared__ float2 sm[NPB];
    int tid = threadIdx.x, bid = blockIdx.x;
    int node0 = bid << 9;
    int nn = min(NPB, N_NODES - node0);
    for (int l = tid; l < nn; l += LTB) sm[l] = h2m[node0 + l];
    __syncthreads();
    float* base = acc2p + (size_t)xcc_id() * (2u * (size_t)N_NODES);
    const u32* r0 = rec + (size_t)bid * CAP;
    u32 n = cnt_g[bid];
    u32 nv = n >> 2;
    for (u32 i = tid; i < nv; i += LTB) {
        v4u r = nt4u(r0 + ((size_t)i << 2));
        float2 v0 = sm[r.x >> 19];
        float2 v1 = sm[r.y >> 19];
        float2 v2 = sm[r.z >> 19];
        float2 v3 = sm[r.w >> 19];
        u32 d0 = (r.x & MASK19) << 1, d1 = (r.y & MASK19) << 1;
        u32 d2 = (r.z & MASK19) << 1, d3 = (r.w & MASK19) << 1;
        faa(base + d0, v0.x); faa(base + d0 + 1, v0.y);
        faa(base + d1, v1.x); faa(base + d1 + 1, v1.y);
        faa(base + d2, v2.x); faa(base + d2 + 1, v2.y);
        faa(base + d3, v3.x); faa(base + d3 + 1, v3.y);
    }
    for (u32 e = (nv << 2) + tid; e < n; e += LTB) {
        u32 r = nt1u(r0 + e);
        float2 v = sm[r >> 19];
        u32 d = (r & MASK19) << 1;
        faa(base + d, v.x);
        faa(base + d + 1, v.y);
    }
    vdrain();
}

// ---- final node pass: out = b2 + d*(sum acc2p + h2m)
__global__ void k_nodeO(const float* __restrict__ dis,
                        const float2* __restrict__ h2m,
                        const float2* __restrict__ acc2p,
                        const float* __restrict__ b2,
                        float2* __restrict__ out, int N) {
    int i = blockIdx.x * blockDim.x + threadIdx.x;
    if (i >= N) return;
    float ax = 0.f, ay = 0.f;
#pragma unroll
    for (int k = 0; k < 8; ++k) {
        float2 a = acc2p[(size_t)k * N_NODES + i];
        ax += a.x; ay += a.y;
    }
    float d = dis[i];
    float2 h = h2m[i];
    out[i] = make_float2(b2[0] + d * (ax + h.x), b2[1] + d * (ay + h.y));
}

// =========================== MID (R9 gather) tier ==========================
__global__ __launch_bounds__(LTB) void m_deg_dis(
        const u32* __restrict__ rec, const u32* __restrict__ cnt_g,
        const float* __restrict__ x,
        float* __restrict__ dis, float* __restrict__ m1) {
    __shared__ u32 cnt[NPB];
    int tid = threadIdx.x, bid = blockIdx.x;
    for (int l = tid; l < NPB; l += LTB) cnt[l] = 0;
    __syncthreads();
    const u32* r0 = rec + (size_t)bid * CAP;
    u32 n = cnt_g[bid];
    u32 nv = n >> 2;
    for (u32 i = tid; i < nv; i += LTB) {
        v4u r = nt4u(r0 + ((size_t)i << 2));
        atomicAdd(&cnt[r.x >> 19], 1u);
        atomicAdd(&cnt[r.y >> 19], 1u);
        atomicAdd(&cnt[r.z >> 19], 1u);
        atomicAdd(&cnt[r.w >> 19], 1u);
    }
    for (u32 e = (nv << 2) + tid; e < n; e += LTB)
        atomicAdd(&cnt[nt1u(r0 + e) >> 19], 1u);
    __syncthreads();
    int node0 = bid << 9;
    int nn = min(NPB, N_NODES - node0);
    for (int l = tid; l < nn; l += LTB) {
        int node = node0 + l;
        float r = rsqrtf((float)(cnt[l] + 1u));
        dis[node] = r;
        m1[node] = r * x[node];
    }
}

__global__ __launch_bounds__(LTB) void m_layer1(
        const u32* __restrict__ rec, const u32* __restrict__ cnt_g,
        const float* __restrict__ dis, const float* __restrict__ m1,
        const float* __restrict__ W1, const float* __restrict__ b1,
        const float* __restrict__ W2, const float* __restrict__ b2,
        float2* __restrict__ h2m, float2* __restrict__ out) {
    __shared__ float acc[NPB];
    int tid = threadIdx.x, bid = blockIdx.x;
    for (int l = tid; l < NPB; l += LTB) acc[l] = 0.f;
    __syncthreads();
    const u32* r0 = rec + (size_t)bid * CAP;
    u32 n = cnt_g[bid];
    u32 nv = n >> 2;
    for (u32 i = tid; i < nv; i += LTB) {
        v4u r = nt4u(r0 + ((size_t)i << 2));
        float v0 = m1[r.x & MASK19];
        float v1 = m1[r.y & MASK19];
        float v2 = m1[r.z & MASK19];
        float v3 = m1[r.w & MASK19];
        atomicAdd(&acc[r.x >> 19], v0);
        atomicAdd(&acc[r.y >> 19], v1);
        atomicAdd(&acc[r.z >> 19], v2);
        atomicAdd(&acc[r.w >> 19], v3);
    }
    for (u32 e = (nv << 2) + tid; e < n; e += LTB) {
        u32 r = nt1u(r0 + e);
        atomicAdd(&acc[r >> 19], m1[r & MASK19]);
    }
    __syncthreads();
    int node0 = bid << 9;
    int nn = min(NPB, N_NODES - node0);
    for (int l = tid; l < nn; l += LTB) {
        int node = node0 + l;
        float d = dis[node];
        float s = d * (acc[l] + m1[node]);
        float a0 = 0.f, a1 = 0.f;
#pragma unroll
        for (int k = 0; k < 8; ++k) {
            float h = fmaxf(W1[k] * s + b1[k], 0.f);
            a0 += h * W2[2 * k + 0];
            a1 += h * W2[2 * k + 1];
        }
        h2m[node] = make_float2(d * a0, d * a1);
        out[node] = make_float2(b2[0] + d * d * a0, b2[1] + d * d * a1);
    }
}

__global__ __launch_bounds__(LTB) void m_layer2(
        const u32* __restrict__ rec, const u32* __restrict__ cnt_g,
        const float* __restrict__ dis, const float2* __restrict__ h2m,
        float2* __restrict__ out) {
    __shared__ float ax[NPB];
    __shared__ float ay[NPB];
    int tid = threadIdx.x, bid = blockIdx.x;
    for (int l = tid; l < NPB; l += LTB) { ax[l] = 0.f; ay[l] = 0.f; }
    __syncthreads();
    const u32* r0 = rec + (size_t)bid * CAP;
    u32 n = cnt_g[bid];
    u32 nv = n >> 2;
    for (u32 i = tid; i < nv; i += LTB) {
        v4u r = nt4u(r0 + ((size_t)i << 2));
        float2 v0 = h2m[r.x & MASK19];
        float2 v1 = h2m[r.y & MASK19];
        float2 v2 = h2m[r.z & MASK19];
        float2 v3 = h2m[r.w & MASK19];
        atomicAdd(&ax[r.x >> 19], v0.x);
        atomicAdd(&ay[r.x >> 19], v0.y);
        atomicAdd(&ax[r.y >> 19], v1.x);
        atomicAdd(&ay[r.y >> 19], v1.y);
        atomicAdd(&ax[r.z >> 19], v2.x);
        atomicAdd(&ay[r.z >> 19], v2.y);
        atomicAdd(&ax[r.w >> 19], v3.x);
        atomicAdd(&ay[r.w >> 19], v3.y);
    }
    for (u32 e = (nv << 2) + tid; e < n; e += LTB) {
        u32 r = nt1u(r0 + e);
        float2 v = h2m[r & MASK19];
        atomicAdd(&ax[r >> 19], v.x);
        atomicAdd(&ay[r >> 19], v.y);
    }
    __syncthreads();
    int node0 = bid << 9;
    int nn = min(NPB, N_NODES - node0);
    for (int l = tid; l < nn; l += LTB) {
        int node = node0 + l;
        float d = dis[node];
        float2 o = out[node];
        out[node] = make_float2(o.x + d * ax[l], o.y + d * ay[l]);
    }
}

// ===========================================================================
// Fallback path (R1): global atomics — only if ws too small (needs 10 MB).
// ===========================================================================
__global__ void f_count_deg(const int* __restrict__ dst, int E,
                            u32* __restrict__ deg) {
    int i = blockIdx.x * blockDim.x + threadIdx.x;
    int stride = gridDim.x * blockDim.x;
    for (int e = i; e < E; e += stride) atomicAdd(&deg[dst[e]], 1u);
}
__global__ void f_dis_sinit(const u32* __restrict__ deg, const float* __restrict__ x,
                            float* __restrict__ dis, float* __restrict__ s, int N) {
    int i = blockIdx.x * blockDim.x + threadIdx.x;
    if (i < N) {
        float r = rsqrtf((float)(deg[i] + 1u));
        dis[i] = r;
        s[i] = r * r * x[i];
    }
}
__global__ void f_agg1(const int* __restrict__ src, const int* __restrict__ dst,
                       int E, const float* __restrict__ dis,
                       const float* __restrict__ x, float* __restrict__ s) {
    int i = blockIdx.x * blockDim.x + threadIdx.x;
    int stride = gridDim.x * blockDim.x;
    for (int e = i; e < E; e += stride) {
        int sj = src[e], dj = dst[e];
        atomicAdd(&s[dj], dis[sj] * dis[dj] * x[sj]);
    }
}
__global__ void f_node2(const float* __restrict__ s, const float* __restrict__ dis,
                        const float* __restrict__ W1, const float* __restrict__ b1,
                        const float* __restrict__ W2, const float* __restrict__ b2,
                        float2* __restrict__ h2, float2* __restrict__ out, int N) {
    int i = blockIdx.x * blockDim.x + threadIdx.x;
    if (i >= N) return;
    float si = s[i];
    float a0 = 0.f, a1 = 0.f;
#pragma unroll
    for (int k = 0; k < 8; ++k) {
        float hk = fmaxf(W1[k] * si + b1[k], 0.f);
        a0 += hk * W2[2 * k + 0];
        a1 += hk * W2[2 * k + 1];
    }
    h2[i] = make_float2(a0, a1);
    float r2 = dis[i] * dis[i];
    out[i] = make_float2(b2[0] + r2 * a0, b2[1] + r2 * a1);
}
__global__ void f_agg2(const int* __restrict__ src, const int* __restrict__ dst,
                       int E, const float* __restrict__ dis,
                       const float2* __restrict__ h2, float* __restrict__ out) {
    int i = blockIdx.x * blockDim.x + threadIdx.x;
    int stride = gridDim.x * blockDim.x;
    for (int e = i; e < E; e += stride) {
        int sj = src[e], dj = dst[e];
        float nm = dis[sj] * dis[dj];
        float2 v = h2[sj];
        atomicAdd(&out[2 * dj + 0], nm * v.x);
        atomicAdd(&out[2 * dj + 1], nm * v.y);
    }
}

// ===========================================================================
extern "C" void kernel_launch(void* const* d_in, const int* in_sizes, int n_in,
                              void* d_out, int out_size, void* d_ws, size_t ws_size,
                              hipStream_t stream) {
    const float* x  = (const float*)d_in[0];
    const int*   ei = (const int*)d_in[1];   // [2,E]: src row, then dst row
    const float* W1 = (const float*)d_in[2];
    const float* b1 = (const float*)d_in[3];
    const float* W2 = (const float*)d_in[4];
    const float* b2 = (const float*)d_in[5];

    const int N = N_NODES;
    const int E = in_sizes[1] / 2;
    const int* src = ei;
    const int* dst = ei + E;
    float* out = (float*)d_out;
    char* ws = (char*)d_ws;
    const int nchunks = (E + CH - 1) / CH;
    const int nodeBlocks = (N + 255) / 256;
    const size_t PHALF = (size_t)8 * N * 4;   // 16 MB (deg / acc1 partials)
    const size_t PFULL = (size_t)8 * N * 8;   // 32 MB (acc2 partials)

    // ---- fast layout: cur | P(32MB) | dis | m1 | h2m | rec ----
    {
        size_t off = 0;
        auto take = [&](size_t bytes) { size_t o = off; off = (off + bytes + 255) & ~(size_t)255; return o; };
        size_t off_cur = take(NBUCK * 4);
        size_t off_P   = take(PFULL);
        size_t off_dis = take((size_t)N * 4);
        size_t off_m1  = take((size_t)N * 4);
        size_t off_h2m = take((size_t)N * 8);
        size_t off_rec = take((size_t)NBUCK * CAP * 4 + 16);
        if (ws_size >= off) {
            u32* cur_g  = (u32*)(ws + off_cur);
            float* P    = (float*)(ws + off_P);
            float* dis  = (float*)(ws + off_dis);
            float* m1   = (float*)(ws + off_m1);
            float2* h2m = (float2*)(ws + off_h2m);
            u32* rec    = (u32*)(ws + off_rec);

            hipMemsetAsync(cur_g, 0, NBUCK * 4, stream);
            hipMemsetAsync(P, 0, PHALF, stream);                  // degp
            k_scatter_fused<1><<<nchunks, STB, 0, stream>>>(src, dst, E,
                                                            cur_g, rec, P);
            k_node1<<<nodeBlocks, 256, 0, stream>>>(P, x, dis, m1, N);
            hipMemsetAsync(P, 0, PHALF, stream);                  // acc1p
            k_l1_scatter<<<NBUCK, LTB, 0, stream>>>(rec, cur_g, m1, P);
            k_node2<<<nodeBlocks, 256, 0, stream>>>(dis, m1, P,
                                                    W1, b1, W2, b2, h2m, N);
            hipMemsetAsync(P, 0, PFULL, stream);                  // acc2p
            k_l2_scatter<<<NBUCK, LTB, 0, stream>>>(rec, cur_g, h2m, P);
            k_nodeO<<<nodeBlocks, 256, 0, stream>>>(dis, h2m, (float2*)P,
                                                    b2, (float2*)out, N);
            return;
        }
    }

    // ---- mid tier (R9 gather path): cur | dis | m1 | h2m | rec ----
    {
        size_t off = 0;
        auto take = [&](size_t bytes) { size_t o = off; off = (off + bytes + 255) & ~(size_t)255; return o; };
        size_t off_cur = take(NBUCK * 4);
        size_t off_dis = take((size_t)N * 4);
        size_t off_m1  = take((size_t)N * 4);
        size_t off_h2m = take((size_t)N * 8);
        size_t off_rec = take((size_t)NBUCK * CAP * 4 + 16);
        if (ws_size >= off) {
            u32* cur_g  = (u32*)(ws + off_cur);
            float* dis  = (float*)(ws + off_dis);
            float* m1   = (float*)(ws + off_m1);
            float2* h2m = (float2*)(ws + off_h2m);
            u32* rec    = (u32*)(ws + off_rec);

            hipMemsetAsync(cur_g, 0, NBUCK * 4, stream);
            k_scatter_fused<0><<<nchunks, STB, 0, stream>>>(src, dst, E,
                                                            cur_g, rec, nullptr);
            m_deg_dis<<<NBUCK, LTB, 0, stream>>>(rec, cur_g, x, dis, m1);
            m_layer1 <<<NBUCK, LTB, 0, stream>>>(rec, cur_g, dis, m1,
                                                 W1, b1, W2, b2,
                                                 h2m, (float2*)out);
            m_layer2 <<<NBUCK, LTB, 0, stream>>>(rec, cur_g, dis, h2m,
                                                 (float2*)out);
            return;
        }
    }

    // ---- fallback: R1 global-atomic path (10 MB ws) ----
    u32* deg    = (u32*)(ws);
    float* dis  = (float*)(ws + (size_t)N * 4);
    float* s    = (float*)(ws + (size_t)N * 8);
    float2* h2  = (float2*)(ws + (size_t)N * 12);
    hipMemsetAsync(deg, 0, (size_t)N * 4, stream);
    int edgeBlocks = (E + 255) / 256;
    f_count_deg<<<edgeBlocks, 256, 0, stream>>>(dst, E, deg);
    f_dis_sinit<<<nodeBlocks, 256, 0, stream>>>(deg, x, dis, s, N);
    f_agg1     <<<edgeBlocks, 256, 0, stream>>>(src, dst, E, dis, x, s);
    f_node2    <<<nodeBlocks, 256, 0, stream>>>(s, dis, W1, b1, W2, b2, h2,
                                                (float2*)out, N);
    f_agg2     <<<edgeBlocks, 256, 0, stream>>>(src, dst, E, dis, h2, out);
}

// Round 7
// 514.887 us; speedup vs baseline: 6.4249x; 6.4249x over previous
//
#include <hip/hip_runtime.h>
#include <hip/hip_fp16.h>

#define N_NODES 500000
typedef unsigned int u32;
typedef unsigned short u16;

// ===========================================================================
// R16: R9 gather structure + fp16-compressed gather arrays for L2 residency.
// R14/R15 post-mortem: global f32/u32 atomics execute MEMORY-SIDE on gfx950
// regardless of scope (WRITE_SIZE ~1GB for 4MB acc) -> scatter orientation
// permanently dead. Gather wall = per-CU outstanding-miss cap (~64) x
// service latency (~450cy = L3-ish): 0.146 req/cy/CU, invariant to ILP &
// occupancy (R10/R13 nulls). Attack the LATENCY term: m1 -> fp16 (1MB),
// h2m -> half2-packed u32 (2MB) so both gather targets stay resident in
// each XCD's 4MB L2 (rec stream is nontemporal). Expect ~2x on l1/l2.
//   rec = dl9<<19 | src19   per 512-node dst bucket.
// ===========================================================================
#define NPB    512
#define NBUCK  ((N_NODES + NPB - 1) / NPB)   // 977
#define CAP    20480          // region capacity; E[fill]=16384, sigma~128 (32σ)
#define CH     8192           // edges per scatter chunk/WG
#define EPT    8              // edges per thread in scatter (CH / 1024)
#define STB    1024           // scatter block
#define LTB    512            // layer/deg block
#define SRC19  0x7FFFFu

typedef unsigned int v4u __attribute__((ext_vector_type(4)));
__device__ inline int  nt1i(const int* p) { return __builtin_nontemporal_load(p); }
__device__ inline u32  nt1u(const u32* p) { return __builtin_nontemporal_load(p); }
__device__ inline v4u  nt4u(const u32* p) { return __builtin_nontemporal_load((const v4u*)p); }

// fp16 helpers (storage = u16 / u32-packed half2; math in f32)
__device__ inline float ldh(const u16* p) {
    __half h = *(const __half*)p;
    return __half2float(h);
}
__device__ inline u16 sth(float v) {
    __half h = __float2half(v);
    return *(u16*)&h;
}
__device__ inline u32 pack2h(float a, float b) {
    union { __half2 h; u32 u; } cvt;
    cvt.h = __floats2half2_rn(a, b);
    return cvt.u;
}
__device__ inline float2 unpack2h(u32 w) {
    union { u32 u; __half2 h; } cvt;
    cvt.u = w;
    return __half22float2(cvt.h);
}

// ---- fused scatter: edges register-cached; LDS histogram + scan + presort;
//      coalesced run writes into fixed bucket regions.  (R9 verbatim)
__global__ __launch_bounds__(STB) void k_scatter_fused(
        const int* __restrict__ src, const int* __restrict__ dst, int E,
        u32* __restrict__ cur_g, u32* __restrict__ rec) {
    __shared__ u32 srec[CH];        // 32 KB
    __shared__ u16 sbk[CH];         // 16 KB
    __shared__ u32 hist[NBUCK];     // 3.9 KB
    __shared__ u32 sc[1024];        // 4 KB
    __shared__ u32 scn_ex[NBUCK];
    __shared__ u32 cur2[NBUCK];
    __shared__ u32 gbase[NBUCK];
    int tid = threadIdx.x, bid = blockIdx.x;
    for (int b = tid; b < NBUCK; b += STB) hist[b] = 0;
    __syncthreads();
    int e0 = bid * CH, e1 = min(E, e0 + CH), n = e1 - e0;
    u32 dv[EPT], sv[EPT];
#pragma unroll
    for (int k = 0; k < EPT; ++k) {
        int e = e0 + (k << 10) + tid;
        if (e < e1) {
            dv[k] = (u32)nt1i(dst + e);
            sv[k] = (u32)nt1i(src + e);
            atomicAdd(&hist[dv[k] >> 9], 1u);
        }
    }
    __syncthreads();
    sc[tid] = (tid < NBUCK) ? hist[tid] : 0u;
    __syncthreads();
    for (int off = 1; off < 1024; off <<= 1) {
        u32 t = (tid >= off) ? sc[tid - off] : 0u;
        __syncthreads();
        sc[tid] += t;
        __syncthreads();
    }
    if (tid < NBUCK) {
        u32 ex = sc[tid] - hist[tid];
        scn_ex[tid] = ex;
        cur2[tid] = ex;
        gbase[tid] = hist[tid] ? atomicAdd(&cur_g[tid], hist[tid]) : 0u;
    }
    __syncthreads();
#pragma unroll
    for (int k = 0; k < EPT; ++k) {
        int e = e0 + (k << 10) + tid;
        if (e < e1) {
            u32 b = dv[k] >> 9;
            u32 p = atomicAdd(&cur2[b], 1u);
            srec[p] = ((dv[k] & (NPB - 1u)) << 19) | sv[k];
            sbk[p] = (u16)b;
        }
    }
    __syncthreads();
    for (int p = tid; p < n; p += STB) {
        u32 b = sbk[p];
        u32 slot = gbase[b] + ((u32)p - scn_ex[b]);
        rec[(size_t)b * CAP + slot] = srec[p];
    }
}

// ---- per-bucket degree -> dis = rsqrt(deg+1) [f32], m1h = fp16(dis*x)
__global__ __launch_bounds__(LTB) void k_deg_dis(
        const u32* __restrict__ rec, const u32* __restrict__ cnt_g,
        const float* __restrict__ x,
        float* __restrict__ dis, u16* __restrict__ m1h) {
    __shared__ u32 cnt[NPB];
    int tid = threadIdx.x, bid = blockIdx.x;
    for (int l = tid; l < NPB; l += LTB) cnt[l] = 0;
    __syncthreads();
    const u32* r0 = rec + (size_t)bid * CAP;
    u32 n = cnt_g[bid];
    u32 nv = n >> 2;
    for (u32 i = tid; i < nv; i += LTB) {
        v4u r = nt4u(r0 + ((size_t)i << 2));
        atomicAdd(&cnt[r.x >> 19], 1u);
        atomicAdd(&cnt[r.y >> 19], 1u);
        atomicAdd(&cnt[r.z >> 19], 1u);
        atomicAdd(&cnt[r.w >> 19], 1u);
    }
    for (u32 e = (nv << 2) + tid; e < n; e += LTB)
        atomicAdd(&cnt[nt1u(r0 + e) >> 19], 1u);
    __syncthreads();
    int node0 = bid << 9;
    int nn = min(NPB, N_NODES - node0);
    for (int l = tid; l < nn; l += LTB) {
        int node = node0 + l;
        float r = rsqrtf((float)(cnt[l] + 1u));   // +1 self-loop; always > 0
        dis[node] = r;
        m1h[node] = sth(r * x[node]);
    }
}

// ---- layer-1: gather fp16 m1h[src] + LDS f32 acc; per-node MLP -> h2mh, out
__global__ __launch_bounds__(LTB) void k_layer1(
        const u32* __restrict__ rec, const u32* __restrict__ cnt_g,
        const float* __restrict__ dis, const u16* __restrict__ m1h,
        const float* __restrict__ W1, const float* __restrict__ b1,
        const float* __restrict__ W2, const float* __restrict__ b2,
        u32* __restrict__ h2mh, float2* __restrict__ out) {
    __shared__ float acc[NPB];
    int tid = threadIdx.x, bid = blockIdx.x;
    for (int l = tid; l < NPB; l += LTB) acc[l] = 0.f;
    __syncthreads();
    const u32* r0 = rec + (size_t)bid * CAP;
    u32 n = cnt_g[bid];
    u32 nv = n >> 2;
    for (u32 i = tid; i < nv; i += LTB) {
        v4u r = nt4u(r0 + ((size_t)i << 2));
        float v0 = ldh(m1h + (r.x & SRC19));
        float v1 = ldh(m1h + (r.y & SRC19));
        float v2 = ldh(m1h + (r.z & SRC19));
        float v3 = ldh(m1h + (r.w & SRC19));
        atomicAdd(&acc[r.x >> 19], v0);
        atomicAdd(&acc[r.y >> 19], v1);
        atomicAdd(&acc[r.z >> 19], v2);
        atomicAdd(&acc[r.w >> 19], v3);
    }
    for (u32 e = (nv << 2) + tid; e < n; e += LTB) {
        u32 r = nt1u(r0 + e);
        atomicAdd(&acc[r >> 19], ldh(m1h + (r & SRC19)));
    }
    __syncthreads();
    int node0 = bid << 9;
    int nn = min(NPB, N_NODES - node0);
    for (int l = tid; l < nn; l += LTB) {
        int node = node0 + l;
        float d = dis[node];
        float s = d * (acc[l] + ldh(m1h + node));
        float a0 = 0.f, a1 = 0.f;
#pragma unroll
        for (int k = 0; k < 8; ++k) {
            float h = fmaxf(W1[k] * s + b1[k], 0.f);
            a0 += h * W2[2 * k + 0];
            a1 += h * W2[2 * k + 1];
        }
        h2mh[node] = pack2h(d * a0, d * a1);                 // fp16 dis[src]*h2
        out[node] = make_float2(b2[0] + d * d * a0, b2[1] + d * d * a1);  // f32 self
    }
}

// ---- layer-2: gather packed half2 h2mh[src] + two LDS planes; out += dis*sum
__global__ __launch_bounds__(LTB) void k_layer2(
        const u32* __restrict__ rec, const u32* __restrict__ cnt_g,
        const float* __restrict__ dis, const u32* __restrict__ h2mh,
        float2* __restrict__ out) {
    __shared__ float ax[NPB];
    __shared__ float ay[NPB];
    int tid = threadIdx.x, bid = blockIdx.x;
    for (int l = tid; l < NPB; l += LTB) { ax[l] = 0.f; ay[l] = 0.f; }
    __syncthreads();
    const u32* r0 = rec + (size_t)bid * CAP;
    u32 n = cnt_g[bid];
    u32 nv = n >> 2;
    for (u32 i = tid; i < nv; i += LTB) {
        v4u r = nt4u(r0 + ((size_t)i << 2));
        float2 v0 = unpack2h(h2mh[r.x & SRC19]);
        float2 v1 = unpack2h(h2mh[r.y & SRC19]);
        float2 v2 = unpack2h(h2mh[r.z & SRC19]);
        float2 v3 = unpack2h(h2mh[r.w & SRC19]);
        atomicAdd(&ax[r.x >> 19], v0.x);
        atomicAdd(&ay[r.x >> 19], v0.y);
        atomicAdd(&ax[r.y >> 19], v1.x);
        atomicAdd(&ay[r.y >> 19], v1.y);
        atomicAdd(&ax[r.z >> 19], v2.x);
        atomicAdd(&ay[r.z >> 19], v2.y);
        atomicAdd(&ax[r.w >> 19], v3.x);
        atomicAdd(&ay[r.w >> 19], v3.y);
    }
    for (u32 e = (nv << 2) + tid; e < n; e += LTB) {
        u32 r = nt1u(r0 + e);
        float2 v = unpack2h(h2mh[r & SRC19]);
        atomicAdd(&ax[r >> 19], v.x);
        atomicAdd(&ay[r >> 19], v.y);
    }
    __syncthreads();
    int node0 = bid << 9;
    int nn = min(NPB, N_NODES - node0);
    for (int l = tid; l < nn; l += LTB) {
        int node = node0 + l;
        float d = dis[node];
        float2 o = out[node];
        out[node] = make_float2(o.x + d * ax[l], o.y + d * ay[l]);
    }
}

// ===========================================================================
// Fallback path (R1): global atomics — only if ws too small (needs 10 MB).
// ===========================================================================
__global__ void f_count_deg(const int* __restrict__ dst, int E,
                            u32* __restrict__ deg) {
    int i = blockIdx.x * blockDim.x + threadIdx.x;
    int stride = gridDim.x * blockDim.x;
    for (int e = i; e < E; e += stride) atomicAdd(&deg[dst[e]], 1u);
}
__global__ void f_dis_sinit(const u32* __restrict__ deg, const float* __restrict__ x,
                            float* __restrict__ dis, float* __restrict__ s, int N) {
    int i = blockIdx.x * blockDim.x + threadIdx.x;
    if (i < N) {
        float r = rsqrtf((float)(deg[i] + 1u));
        dis[i] = r;
        s[i] = r * r * x[i];
    }
}
__global__ void f_agg1(const int* __restrict__ src, const int* __restrict__ dst,
                       int E, const float* __restrict__ dis,
                       const float* __restrict__ x, float* __restrict__ s) {
    int i = blockIdx.x * blockDim.x + threadIdx.x;
    int stride = gridDim.x * blockDim.x;
    for (int e = i; e < E; e += stride) {
        int sj = src[e], dj = dst[e];
        atomicAdd(&s[dj], dis[sj] * dis[dj] * x[sj]);
    }
}
__global__ void f_node2(const float* __restrict__ s, const float* __restrict__ dis,
                        const float* __restrict__ W1, const float* __restrict__ b1,
                        const float* __restrict__ W2, const float* __restrict__ b2,
                        float2* __restrict__ h2, float2* __restrict__ out, int N) {
    int i = blockIdx.x * blockDim.x + threadIdx.x;
    if (i >= N) return;
    float si = s[i];
    float a0 = 0.f, a1 = 0.f;
#pragma unroll
    for (int k = 0; k < 8; ++k) {
        float hk = fmaxf(W1[k] * si + b1[k], 0.f);
        a0 += hk * W2[2 * k + 0];
        a1 += hk * W2[2 * k + 1];
    }
    h2[i] = make_float2(a0, a1);
    float r2 = dis[i] * dis[i];
    out[i] = make_float2(b2[0] + r2 * a0, b2[1] + r2 * a1);
}
__global__ void f_agg2(const int* __restrict__ src, const int* __restrict__ dst,
                       int E, const float* __restrict__ dis,
                       const float2* __restrict__ h2, float* __restrict__ out) {
    int i = blockIdx.x * blockDim.x + threadIdx.x;
    int stride = gridDim.x * blockDim.x;
    for (int e = i; e < E; e += stride) {
        int sj = src[e], dj = dst[e];
        float nm = dis[sj] * dis[dj];
        float2 v = h2[sj];
        atomicAdd(&out[2 * dj + 0], nm * v.x);
        atomicAdd(&out[2 * dj + 1], nm * v.y);
    }
}

// ===========================================================================
extern "C" void kernel_launch(void* const* d_in, const int* in_sizes, int n_in,
                              void* d_out, int out_size, void* d_ws, size_t ws_size,
                              hipStream_t stream) {
    const float* x  = (const float*)d_in[0];
    const int*   ei = (const int*)d_in[1];   // [2,E]: src row, then dst row
    const float* W1 = (const float*)d_in[2];
    const float* b1 = (const float*)d_in[3];
    const float* W2 = (const float*)d_in[4];
    const float* b2 = (const float*)d_in[5];

    const int N = N_NODES;
    const int E = in_sizes[1] / 2;
    const int* src = ei;
    const int* dst = ei + E;
    float* out = (float*)d_out;
    char* ws = (char*)d_ws;

    // ---- fast-path workspace: cur | dis | m1h | h2mh | rec  (~85 MB) ----
    size_t off = 0;
    auto take = [&](size_t bytes) { size_t o = off; off = (off + bytes + 255) & ~(size_t)255; return o; };
    size_t off_cur  = take(NBUCK * 4);
    size_t off_dis  = take((size_t)N * 4);
    size_t off_m1h  = take((size_t)N * 2);
    size_t off_h2mh = take((size_t)N * 4);
    size_t off_rec  = take((size_t)NBUCK * CAP * 4 + 16);   // ~80 MB
    size_t need     = off;

    if (ws_size >= need) {
        u32* cur_g  = (u32*)(ws + off_cur);
        float* dis  = (float*)(ws + off_dis);
        u16* m1h    = (u16*)(ws + off_m1h);
        u32* h2mh   = (u32*)(ws + off_h2mh);
        u32* rec    = (u32*)(ws + off_rec);

        hipMemsetAsync(cur_g, 0, NBUCK * 4, stream);
        const int nchunks = (E + CH - 1) / CH;
        k_scatter_fused<<<nchunks, STB, 0, stream>>>(src, dst, E, cur_g, rec);
        k_deg_dis      <<<NBUCK,   LTB, 0, stream>>>(rec, cur_g, x, dis, m1h);
        k_layer1       <<<NBUCK,   LTB, 0, stream>>>(rec, cur_g, dis, m1h,
                                                     W1, b1, W2, b2,
                                                     h2mh, (float2*)out);
        k_layer2       <<<NBUCK,   LTB, 0, stream>>>(rec, cur_g, dis, h2mh,
                                                     (float2*)out);
        return;
    }

    // ---- fallback: R1 global-atomic path (10 MB ws) ----
    u32* deg    = (u32*)(ws);
    float* dis  = (float*)(ws + (size_t)N * 4);
    float* s    = (float*)(ws + (size_t)N * 8);
    float2* h2  = (float2*)(ws + (size_t)N * 12);
    hipMemsetAsync(deg, 0, (size_t)N * 4, stream);
    int nodeBlocks = (N + 255) / 256;
    int edgeBlocks = (E + 255) / 256;
    f_count_deg<<<edgeBlocks, 256, 0, stream>>>(dst, E, deg);
    f_dis_sinit<<<nodeBlocks, 256, 0, stream>>>(deg, x, dis, s, N);
    f_agg1     <<<edgeBlocks, 256, 0, stream>>>(src, dst, E, dis, x, s);
    f_node2    <<<nodeBlocks, 256, 0, stream>>>(s, dis, W1, b1, W2, b2, h2,
                                                (float2*)out, N);
    f_agg2     <<<edgeBlocks, 256, 0, stream>>>(src, dst, E, dis, h2, out);
}